// Round 5
// baseline (189.935 us; speedup 1.0000x reference)
//
#include <hip/hip_runtime.h>
#include <hip/hip_bf16.h>
#include <float.h>
#include <math.h>

typedef short short8 __attribute__((ext_vector_type(8)));
typedef float f32x4  __attribute__((ext_vector_type(4)));

#define KEPS   1e-5f
#define DENOMC 1e-5f

__device__ __forceinline__ short f2bf(float x) {
    return __builtin_bit_cast(short, __float2bfloat16(x));
}

// async global->LDS, 16 B per lane, per-lane global src, wave-uniform LDS dest
__device__ __forceinline__ void gload_lds16(const void* g, void* l) {
    __builtin_amdgcn_global_load_lds(
        (const __attribute__((address_space(1))) void*)g,
        (__attribute__((address_space(3))) void*)l,
        16, 0, 0);
}

// unsorted top-10, slot 0 always holds the min (admission gate)
__device__ __forceinline__ void top10_insert(float (&lst)[10], float s) {
    if (s > lst[0]) {
        lst[0] = s;
        #pragma unroll
        for (int i = 1; i < 10; ++i) {
            float lo = fminf(lst[0], lst[i]);
            float hi = fmaxf(lst[0], lst[i]);
            lst[0] = lo; lst[i] = hi;
        }
    }
}

// ---------------------------------------------------------------------------
// Kernel 1: stream memory once, staged through double-buffered LDS via
// global_load_lds. THIS ROUND: contiguous per-block tile ranges (block bid
// streams ~200 KB sequentially) instead of grid-stride 10.5-MB jumps.
// Role-swapped MFMA: A = -2*q, B = memory rows, C = splat(row norm).
// ---------------------------------------------------------------------------
__global__ __launch_bounds__(256, 5) void ep_main(
    const float* __restrict__ q, const float* __restrict__ mem,
    float* __restrict__ part_top,    // [64][nb][10]
    float* __restrict__ part_sums,   // [33][nb]
    int nb, int ntiles)
{
    __shared__ float smem[4224];     // 2 x 8 KB staging; ltop overlays later
    __shared__ float red[4][4][8];
    __shared__ float ssred[4];

    const int tid  = threadIdx.x;
    const int lane = tid & 63;
    const int wave = tid >> 6;
    const int g    = lane >> 4;   // k-chunk group (0..3), k = 8g..8g+7
    const int c    = lane & 15;   // memrow-within-wave-subtile
    const int bid  = blockIdx.x;

    // contiguous tile range for this block
    const int tpb = ntiles / nb;
    const int rem = ntiles % nb;
    const int t0  = bid * tpb + (bid < rem ? bid : rem);
    const int cnt = tpb + (bid < rem ? 1 : 0);

    // A fragments (M x K = 16 x 32): lane holds -2*q[16h + c][8g .. 8g+8)
    short8 qfrag[4];
    #pragma unroll
    for (int h = 0; h < 4; ++h) {
        const float* qp = q + (h * 16 + c) * 32 + g * 8;
        f32x4 w0 = *(const f32x4*)qp;
        f32x4 w1 = *(const f32x4*)(qp + 4);
        short8 f;
        f[0]=f2bf(-2.f*w0[0]); f[1]=f2bf(-2.f*w0[1]); f[2]=f2bf(-2.f*w0[2]); f[3]=f2bf(-2.f*w0[3]);
        f[4]=f2bf(-2.f*w1[0]); f[5]=f2bf(-2.f*w1[1]); f[6]=f2bf(-2.f*w1[2]); f[7]=f2bf(-2.f*w1[3]);
        qfrag[h] = f;
    }

    float t1[16];                 // top-1 per query 16h+4g+r
    #pragma unroll
    for (int i = 0; i < 16; ++i) t1[i] = -FLT_MAX;
    float cs[8];
    #pragma unroll
    for (int r = 0; r < 8; ++r) cs[r] = 0.f;
    float sumsq = 0.f;

    // staging addresses: thread T fills physical granules T, T+256; source
    // granule swizzled S(z)=z^(((z>>3)&3)<<1) (involution on bits 1-2 / 3-4)
    const int    swz  = ((tid >> 3) & 3) << 1;
    const size_t off0 = (size_t)(tid ^ swz) * 16;
    char* lds_d0[2], * lds_d1[2];
    #pragma unroll
    for (int b = 0; b < 2; ++b) {
        lds_d0[b] = (char*)smem + b * 8192 + wave * 1024;
        lds_d1[b] = (char*)smem + b * 8192 + 4096 + wave * 1024;
    }
    const int    Y0    = wave * 128 + c * 8 + g * 2;
    const size_t rdoff = (size_t)(Y0 ^ ((c & 3) << 1)) * 16;

    auto process = [&](const float* buf) {
        const f32x4* rp = (const f32x4*)((const char*)buf + rdoff);
        f32x4 v0 = rp[0];
        f32x4 v1 = rp[1];

        float ps;
        ps = v0[0] * v0[0];
        ps = fmaf(v0[1], v0[1], ps);
        ps = fmaf(v0[2], v0[2], ps);
        ps = fmaf(v0[3], v0[3], ps);
        ps = fmaf(v1[0], v1[0], ps);
        ps = fmaf(v1[1], v1[1], ps);
        ps = fmaf(v1[2], v1[2], ps);
        ps = fmaf(v1[3], v1[3], ps);
        sumsq += ps;
        cs[0] += v0[0]; cs[1] += v0[1]; cs[2] += v0[2]; cs[3] += v0[3];
        cs[4] += v1[0]; cs[5] += v1[1]; cs[6] += v1[2]; cs[7] += v1[3];

        float m2 = ps + __shfl_xor(ps, 16, 64);
        m2 = m2 + __shfl_xor(m2, 32, 64);
        f32x4 mi = {m2, m2, m2, m2};

        short8 mf;
        mf[0]=f2bf(v0[0]); mf[1]=f2bf(v0[1]); mf[2]=f2bf(v0[2]); mf[3]=f2bf(v0[3]);
        mf[4]=f2bf(v1[0]); mf[5]=f2bf(v1[1]); mf[6]=f2bf(v1[2]); mf[7]=f2bf(v1[3]);

        #pragma unroll
        for (int h = 0; h < 4; ++h) {
            f32x4 acc = __builtin_amdgcn_mfma_f32_16x16x32_bf16(qfrag[h], mf, mi, 0, 0, 0);
            t1[h*4+0] = fmaxf(t1[h*4+0], acc[0]);
            t1[h*4+1] = fmaxf(t1[h*4+1], acc[1]);
            t1[h*4+2] = fmaxf(t1[h*4+2], acc[2]);
            t1[h*4+3] = fmaxf(t1[h*4+3], acc[3]);
        }
    };

    // ---- LDS double-buffered contiguous stream ----
    const char* msrc = (const char*)mem + (size_t)t0 * 8192 + off0;
    gload_lds16(msrc,        lds_d0[0]);
    gload_lds16(msrc + 4096, lds_d1[0]);
    msrc += 8192;

    int cur = 0;
    for (int i = 0; ; ++i) {
        __syncthreads();                  // buf[cur] complete everywhere
        const bool more = (i + 1) < cnt;
        if (more) {
            gload_lds16(msrc,        lds_d0[cur ^ 1]);
            gload_lds16(msrc + 4096, lds_d1[cur ^ 1]);
            msrc += 8192;
        }
        process(smem + cur * 2048);
        if (!more) break;
        __syncthreads();                  // readers done before overwrite
        cur ^= 1;
    }

    // ---- block-level merge (ltop overlays the staging LDS) ----
    __syncthreads();
    float (*ltop)[65] = (float (*)[65])smem;   // [query][stream=w*16+c]

    const int col = wave * 16 + c;
    #pragma unroll
    for (int h = 0; h < 4; ++h) {
        #pragma unroll
        for (int r = 0; r < 4; ++r)
            ltop[h * 16 + g * 4 + r][col] = t1[h * 4 + r];
    }

    #pragma unroll
    for (int r = 0; r < 8; ++r) {
        float v = cs[r];
        v += __shfl_xor(v, 1, 64);
        v += __shfl_xor(v, 2, 64);
        v += __shfl_xor(v, 4, 64);
        v += __shfl_xor(v, 8, 64);
        cs[r] = v;
    }
    float ssv = sumsq;
    ssv += __shfl_xor(ssv, 1, 64);
    ssv += __shfl_xor(ssv, 2, 64);
    ssv += __shfl_xor(ssv, 4, 64);
    ssv += __shfl_xor(ssv, 8, 64);
    ssv += __shfl_xor(ssv, 16, 64);
    ssv += __shfl_xor(ssv, 32, 64);
    if (c == 0) {
        #pragma unroll
        for (int r = 0; r < 8; ++r) red[wave][g][r] = cs[r];
    }
    if (lane == 0) ssred[wave] = ssv;
    __syncthreads();

    if (tid < 32) {
        float a = red[0][tid >> 3][tid & 7] + red[1][tid >> 3][tid & 7]
                + red[2][tid >> 3][tid & 7] + red[3][tid >> 3][tid & 7];
        part_sums[(size_t)tid * nb + bid] = a;
    } else if (tid == 32) {
        part_sums[(size_t)32 * nb + bid] = ssred[0] + ssred[1] + ssred[2] + ssred[3];
    }

    if (tid < 64) {
        float lst[10];
        #pragma unroll
        for (int i = 0; i < 10; ++i) lst[i] = -FLT_MAX;
        #pragma unroll 4
        for (int s2 = 0; s2 < 64; ++s2) top10_insert(lst, ltop[tid][s2]);
        #pragma unroll
        for (int i = 0; i < 10; ++i)
            part_top[((size_t)tid * nb + bid) * 10 + i] = lst[i];
    }
}

// ---------------------------------------------------------------------------
// Kernel 2 (fused tail): 64 blocks, one per query.
// ---------------------------------------------------------------------------
__global__ __launch_bounds__(256) void ep_tail(
    const float* __restrict__ q, const float* __restrict__ part_top,
    const float* __restrict__ part_sums, float* __restrict__ out,
    int nb, int Mrows)
{
    const int b    = blockIdx.x;
    const int tid  = threadIdx.x;
    const int lane = tid & 63;
    const int wave = tid >> 6;

    __shared__ float smem[256 * 33];
    __shared__ float colsum_a[33];
    __shared__ float w4[4];
    __shared__ float mean_s, q2_s;

    if (tid < 64) {
        float x = (tid < 32) ? q[b * 32 + tid] : 0.f;
        float a = x * x;
        a += __shfl_xor(a, 1, 64);
        a += __shfl_xor(a, 2, 64);
        a += __shfl_xor(a, 4, 64);
        a += __shfl_xor(a, 8, 64);
        a += __shfl_xor(a, 16, 64);
        if (tid == 0) q2_s = a;
    }

    float a2 = 0.f;
    #pragma unroll
    for (int e = 0; e < 8; ++e) {
        float x = q[tid * 8 + e];
        a2 = fmaf(x, x, a2);
    }
    a2 += __shfl_xor(a2, 1, 64);
    a2 += __shfl_xor(a2, 2, 64);
    a2 += __shfl_xor(a2, 4, 64);
    a2 += __shfl_xor(a2, 8, 64);
    a2 += __shfl_xor(a2, 16, 64);
    a2 += __shfl_xor(a2, 32, 64);
    if (lane == 0) w4[wave] = a2;

    float acc[33];
    #pragma unroll
    for (int c2 = 0; c2 < 33; ++c2) acc[c2] = 0.f;
    for (int i = tid; i < nb; i += 256) {
        #pragma unroll
        for (int c2 = 0; c2 < 33; ++c2) acc[c2] += part_sums[(size_t)c2 * nb + i];
    }
    #pragma unroll
    for (int c2 = 0; c2 < 33; ++c2) smem[tid * 33 + c2] = acc[c2];
    __syncthreads();
    if (tid < 33) {
        float a = 0.f;
        #pragma unroll 16
        for (int j = 0; j < 256; ++j) a += smem[j * 33 + tid];
        colsum_a[tid] = a;
    }
    __syncthreads();

    if (tid < 32) {
        float qs = 0.f;
        #pragma unroll 8
        for (int bb = 0; bb < 64; ++bb) qs += q[bb * 32 + tid];
        float dq = qs * colsum_a[tid];
        dq += __shfl_xor(dq, 1, 64);
        dq += __shfl_xor(dq, 2, 64);
        dq += __shfl_xor(dq, 4, 64);
        dq += __shfl_xor(dq, 8, 64);
        dq += __shfl_xor(dq, 16, 64);
        if (tid == 0) {
            double q2sum = (double)w4[0] + (double)w4[1] + (double)w4[2] + (double)w4[3];
            double sumsq = (double)colsum_a[32];
            double Md    = (double)Mrows;
            mean_s = (float)((Md * q2sum + 64.0 * sumsq - 2.0 * (double)dq) / (64.0 * Md));
        }
    }
    __syncthreads();

    float lst[10];
    #pragma unroll
    for (int i = 0; i < 10; ++i) lst[i] = -FLT_MAX;
    const float* pt = part_top + (size_t)b * nb * 10;
    for (int i = tid; i < nb; i += 256) {
        const float* pp = pt + (size_t)i * 10;
        #pragma unroll
        for (int r = 0; r < 10; ++r) top10_insert(lst, pp[r]);
    }
    #pragma unroll
    for (int r = 0; r < 10; ++r) smem[tid * 10 + r] = lst[r];
    __syncthreads();

    if (tid < 32) {
        float m[10];
        #pragma unroll
        for (int i = 0; i < 10; ++i) m[i] = -FLT_MAX;
        for (int j2 = 0; j2 < 8; ++j2) {
            #pragma unroll
            for (int r = 0; r < 10; ++r) top10_insert(m, smem[(tid * 8 + j2) * 10 + r]);
        }
        #pragma unroll
        for (int r = 0; r < 10; ++r) smem[2560 + tid * 10 + r] = m[r];
    }
    __syncthreads();

    if (tid == 0) {
        float m[10];
        #pragma unroll
        for (int i = 0; i < 10; ++i) m[i] = -FLT_MAX;
        for (int j2 = 0; j2 < 32; ++j2) {
            #pragma unroll
            for (int r = 0; r < 10; ++r) top10_insert(m, smem[2560 + j2 * 10 + r]);
        }
        const float mean = mean_s;
        const float q2b  = q2_s;
        float sum = 0.f;
        #pragma unroll
        for (int r = 0; r < 10; ++r) {
            float sq = m[r] + q2b;
            sq = fmaxf(sq, 0.f);
            sum += KEPS / (sq / mean + KEPS);
        }
        out[b] = 1.0f / sqrtf(sum + DENOMC);
    }
}

// ---------------------------------------------------------------------------
// MEASUREMENT ROUND: each kernel launched twice (idempotent, deterministic).
// T = 2*main_contig + 2*tail;  R4 baseline: main_gridstride + tail = 98 us.
// ---------------------------------------------------------------------------
extern "C" void kernel_launch(void* const* d_in, const int* in_sizes, int n_in,
                              void* d_out, int out_size, void* d_ws, size_t ws_size,
                              hipStream_t stream)
{
    const float* q   = (const float*)d_in[0];
    const float* mem = (const float*)d_in[1];
    float* out = (float*)d_out;

    const int Mrows  = in_sizes[1] / 32;   // 2,000,000
    const int ntiles = Mrows / 64;         // 31,250

    int nb = 1280;                         // 256 CUs x 5 resident blocks
    while (nb > 64 && ((size_t)nb * 673 + 64) * sizeof(float) > ws_size) nb >>= 1;
    if (nb > ntiles) nb = ntiles;

    float* part_top  = (float*)d_ws;                         // [64][nb][10]
    float* part_sums = part_top + (size_t)64 * nb * 10;      // [33][nb]

    ep_main<<<dim3(nb), dim3(256), 0, stream>>>(q, mem, part_top, part_sums, nb, ntiles);
    ep_main<<<dim3(nb), dim3(256), 0, stream>>>(q, mem, part_top, part_sums, nb, ntiles);
    ep_tail<<<dim3(64), dim3(256), 0, stream>>>(q, part_top, part_sums, out, nb, Mrows);
    ep_tail<<<dim3(64), dim3(256), 0, stream>>>(q, part_top, part_sums, out, nb, Mrows);
}

// Round 6
// 96.517 us; speedup vs baseline: 1.9679x; 1.9679x over previous
//
#include <hip/hip_runtime.h>
#include <hip/hip_bf16.h>
#include <float.h>
#include <math.h>

typedef short short8 __attribute__((ext_vector_type(8)));
typedef float f32x4  __attribute__((ext_vector_type(4)));

#define KEPS   1e-5f
#define DENOMC 1e-5f

__device__ __forceinline__ short f2bf(float x) {
    return __builtin_bit_cast(short, __float2bfloat16(x));
}

// async global->LDS, 16 B per lane, per-lane global src, wave-uniform LDS dest
__device__ __forceinline__ void gload_lds16(const void* g, void* l) {
    __builtin_amdgcn_global_load_lds(
        (const __attribute__((address_space(1))) void*)g,
        (__attribute__((address_space(3))) void*)l,
        16, 0, 0);
}

// unsorted top-10, slot 0 always holds the min (admission gate)
__device__ __forceinline__ void top10_insert(float (&lst)[10], float s) {
    if (s > lst[0]) {
        lst[0] = s;
        #pragma unroll
        for (int i = 1; i < 10; ++i) {
            float lo = fminf(lst[0], lst[i]);
            float hi = fmaxf(lst[0], lst[i]);
            lst[0] = lo; lst[i] = hi;
        }
    }
}

// ---------------------------------------------------------------------------
// Kernel 1: stream memory once through a PER-WAVE-PRIVATE 4-deep LDS ring.
// Each wave stages exactly the 2-KB tile-slice it will read -> no cross-wave
// deps -> ZERO barriers in the loop; ordering via counted s_waitcnt vmcnt(N)
// (6 loads = 3 tiles stay in flight; never drained to 0 in steady state).
// Outstanding bytes/CU: ~40 KB (R4) -> ~120-160 KB (this round's variable).
// Role-swapped MFMA: A = -2*q, B = memory rows, C = splat(row norm).
// ---------------------------------------------------------------------------
__global__ __launch_bounds__(256, 5) void ep_main(
    const float* __restrict__ q, const float* __restrict__ mem,
    float* __restrict__ part_top,    // [64][nb][10]
    float* __restrict__ part_sums,   // [33][nb]
    int nb, int ntiles)
{
    __shared__ __align__(16) char smemc[32768];   // [wave][4 slots][2048 B]

    const int tid  = threadIdx.x;
    const int lane = tid & 63;
    const int wave = tid >> 6;
    const int g    = lane >> 4;   // k-chunk group (0..3)
    const int c    = lane & 15;   // memrow-within-wave-slice
    const int bid  = blockIdx.x;

    // contiguous tile range for this block
    const int tpb = ntiles / nb;
    const int rem = ntiles % nb;
    const int t0  = bid * tpb + (bid < rem ? bid : rem);
    const int cnt = tpb + (bid < rem ? 1 : 0);

    // A fragments (M x K = 16 x 32): lane holds -2*q[16h + c][8g .. 8g+8)
    short8 qfrag[4];
    #pragma unroll
    for (int h = 0; h < 4; ++h) {
        const float* qp = q + (h * 16 + c) * 32 + g * 8;
        f32x4 w0 = *(const f32x4*)qp;
        f32x4 w1 = *(const f32x4*)(qp + 4);
        short8 f;
        f[0]=f2bf(-2.f*w0[0]); f[1]=f2bf(-2.f*w0[1]); f[2]=f2bf(-2.f*w0[2]); f[3]=f2bf(-2.f*w0[3]);
        f[4]=f2bf(-2.f*w1[0]); f[5]=f2bf(-2.f*w1[1]); f[6]=f2bf(-2.f*w1[2]); f[7]=f2bf(-2.f*w1[3]);
        qfrag[h] = f;
    }

    float t1[16];                 // top-1 per query 16h+4g+r
    #pragma unroll
    for (int i = 0; i < 16; ++i) t1[i] = -FLT_MAX;
    float cs[8];
    #pragma unroll
    for (int r = 0; r < 8; ++r) cs[r] = 0.f;
    float sumsq = 0.f;

    // per-wave ring base; slice-local XOR swizzle (involution on granule
    // bits 1-2 ^= bits 3-4) applied on the GLOBAL SOURCE, linear LDS dest
    char* ring = smemc + wave * 8192;
    const int    sw    = ((lane >> 3) & 3) << 1;
    const size_t so    = (size_t)((lane ^ sw) * 16);      // within 1-KB half
    const size_t rdoff = (size_t)(((c * 8 + g * 2) ^ ((c & 3) << 1)) * 16);

    auto process = [&](const char* buf) {
        const f32x4* rp = (const f32x4*)(buf + rdoff);
        f32x4 v0 = rp[0];
        f32x4 v1 = rp[1];

        float ps;
        ps = v0[0] * v0[0];
        ps = fmaf(v0[1], v0[1], ps);
        ps = fmaf(v0[2], v0[2], ps);
        ps = fmaf(v0[3], v0[3], ps);
        ps = fmaf(v1[0], v1[0], ps);
        ps = fmaf(v1[1], v1[1], ps);
        ps = fmaf(v1[2], v1[2], ps);
        ps = fmaf(v1[3], v1[3], ps);
        sumsq += ps;
        cs[0] += v0[0]; cs[1] += v0[1]; cs[2] += v0[2]; cs[3] += v0[3];
        cs[4] += v1[0]; cs[5] += v1[1]; cs[6] += v1[2]; cs[7] += v1[3];

        // row norm of slice-row c: reduce ps across the 4 k-groups
        float m2 = ps + __shfl_xor(ps, 16, 64);
        m2 = m2 + __shfl_xor(m2, 32, 64);
        f32x4 mi = {m2, m2, m2, m2};

        short8 mf;
        mf[0]=f2bf(v0[0]); mf[1]=f2bf(v0[1]); mf[2]=f2bf(v0[2]); mf[3]=f2bf(v0[3]);
        mf[4]=f2bf(v1[0]); mf[5]=f2bf(v1[1]); mf[6]=f2bf(v1[2]); mf[7]=f2bf(v1[3]);

        #pragma unroll
        for (int h = 0; h < 4; ++h) {
            f32x4 acc = __builtin_amdgcn_mfma_f32_16x16x32_bf16(qfrag[h], mf, mi, 0, 0, 0);
            t1[h*4+0] = fmaxf(t1[h*4+0], acc[0]);
            t1[h*4+1] = fmaxf(t1[h*4+1], acc[1]);
            t1[h*4+2] = fmaxf(t1[h*4+2], acc[2]);
            t1[h*4+3] = fmaxf(t1[h*4+3], acc[3]);
        }
    };

    // ---- barrier-free 4-deep pipeline ----
    const char* gstage = (const char*)mem + (size_t)t0 * 8192 + (size_t)wave * 2048 + so;

    const int nst = cnt < 3 ? cnt : 3;
    for (int d = 0; d < nst; ++d) {               // prologue: tiles 0..2
        char* dst = ring + (d & 3) * 2048;
        gload_lds16(gstage,        dst);
        gload_lds16(gstage + 1024, dst + 1024);
        gstage += 8192;
    }
    for (int i = 0; i + 3 < cnt; ++i) {           // steady state
        char* dst = ring + ((i + 3) & 3) * 2048;
        gload_lds16(gstage,        dst);
        gload_lds16(gstage + 1024, dst + 1024);
        gstage += 8192;
        asm volatile("s_waitcnt vmcnt(6)" ::: "memory");   // tile i complete
        process(ring + (i & 3) * 2048);
    }
    if (cnt >= 3) {                               // epilogue drain 4->2->0
        asm volatile("s_waitcnt vmcnt(4)" ::: "memory");
        process(ring + ((cnt - 3) & 3) * 2048);
    }
    if (cnt >= 2) {
        asm volatile("s_waitcnt vmcnt(2)" ::: "memory");
        process(ring + ((cnt - 2) & 3) * 2048);
    }
    asm volatile("s_waitcnt vmcnt(0)" ::: "memory");
    process(ring + ((cnt - 1) & 3) * 2048);

    // ---- block-level merge (overlays the ring; one barrier re-syncs) ----
    __syncthreads();
    float (*ltop)[65] = (float (*)[65])smemc;              // 16640 B
    float (*red)[4][8] = (float (*)[4][8])(smemc + 16640); // 512 B
    float* ssred = (float*)(smemc + 17152);                // 16 B

    const int col = wave * 16 + c;
    #pragma unroll
    for (int h = 0; h < 4; ++h) {
        #pragma unroll
        for (int r = 0; r < 4; ++r)
            ltop[h * 16 + g * 4 + r][col] = t1[h * 4 + r];
    }

    #pragma unroll
    for (int r = 0; r < 8; ++r) {
        float v = cs[r];
        v += __shfl_xor(v, 1, 64);
        v += __shfl_xor(v, 2, 64);
        v += __shfl_xor(v, 4, 64);
        v += __shfl_xor(v, 8, 64);
        cs[r] = v;
    }
    float ssv = sumsq;
    ssv += __shfl_xor(ssv, 1, 64);
    ssv += __shfl_xor(ssv, 2, 64);
    ssv += __shfl_xor(ssv, 4, 64);
    ssv += __shfl_xor(ssv, 8, 64);
    ssv += __shfl_xor(ssv, 16, 64);
    ssv += __shfl_xor(ssv, 32, 64);
    if (c == 0) {
        #pragma unroll
        for (int r = 0; r < 8; ++r) red[wave][g][r] = cs[r];
    }
    if (lane == 0) ssred[wave] = ssv;
    __syncthreads();

    if (tid < 32) {
        float a = red[0][tid >> 3][tid & 7] + red[1][tid >> 3][tid & 7]
                + red[2][tid >> 3][tid & 7] + red[3][tid >> 3][tid & 7];
        part_sums[(size_t)tid * nb + bid] = a;
    } else if (tid == 32) {
        part_sums[(size_t)32 * nb + bid] = ssred[0] + ssred[1] + ssred[2] + ssred[3];
    }

    if (tid < 64) {
        float lst[10];
        #pragma unroll
        for (int i = 0; i < 10; ++i) lst[i] = -FLT_MAX;
        #pragma unroll 4
        for (int s2 = 0; s2 < 64; ++s2) top10_insert(lst, ltop[tid][s2]);
        #pragma unroll
        for (int i = 0; i < 10; ++i)
            part_top[((size_t)tid * nb + bid) * 10 + i] = lst[i];
    }
}

// ---------------------------------------------------------------------------
// Kernel 2 (fused tail): 64 blocks, one per query.
// ---------------------------------------------------------------------------
__global__ __launch_bounds__(256) void ep_tail(
    const float* __restrict__ q, const float* __restrict__ part_top,
    const float* __restrict__ part_sums, float* __restrict__ out,
    int nb, int Mrows)
{
    const int b    = blockIdx.x;
    const int tid  = threadIdx.x;
    const int lane = tid & 63;
    const int wave = tid >> 6;

    __shared__ float smem[256 * 33];
    __shared__ float colsum_a[33];
    __shared__ float w4[4];
    __shared__ float mean_s, q2_s;

    if (tid < 64) {
        float x = (tid < 32) ? q[b * 32 + tid] : 0.f;
        float a = x * x;
        a += __shfl_xor(a, 1, 64);
        a += __shfl_xor(a, 2, 64);
        a += __shfl_xor(a, 4, 64);
        a += __shfl_xor(a, 8, 64);
        a += __shfl_xor(a, 16, 64);
        if (tid == 0) q2_s = a;
    }

    float a2 = 0.f;
    #pragma unroll
    for (int e = 0; e < 8; ++e) {
        float x = q[tid * 8 + e];
        a2 = fmaf(x, x, a2);
    }
    a2 += __shfl_xor(a2, 1, 64);
    a2 += __shfl_xor(a2, 2, 64);
    a2 += __shfl_xor(a2, 4, 64);
    a2 += __shfl_xor(a2, 8, 64);
    a2 += __shfl_xor(a2, 16, 64);
    a2 += __shfl_xor(a2, 32, 64);
    if (lane == 0) w4[wave] = a2;

    float acc[33];
    #pragma unroll
    for (int c2 = 0; c2 < 33; ++c2) acc[c2] = 0.f;
    for (int i = tid; i < nb; i += 256) {
        #pragma unroll
        for (int c2 = 0; c2 < 33; ++c2) acc[c2] += part_sums[(size_t)c2 * nb + i];
    }
    #pragma unroll
    for (int c2 = 0; c2 < 33; ++c2) smem[tid * 33 + c2] = acc[c2];
    __syncthreads();
    if (tid < 33) {
        float a = 0.f;
        #pragma unroll 16
        for (int j = 0; j < 256; ++j) a += smem[j * 33 + tid];
        colsum_a[tid] = a;
    }
    __syncthreads();

    if (tid < 32) {
        float qs = 0.f;
        #pragma unroll 8
        for (int bb = 0; bb < 64; ++bb) qs += q[bb * 32 + tid];
        float dq = qs * colsum_a[tid];
        dq += __shfl_xor(dq, 1, 64);
        dq += __shfl_xor(dq, 2, 64);
        dq += __shfl_xor(dq, 4, 64);
        dq += __shfl_xor(dq, 8, 64);
        dq += __shfl_xor(dq, 16, 64);
        if (tid == 0) {
            double q2sum = (double)w4[0] + (double)w4[1] + (double)w4[2] + (double)w4[3];
            double sumsq = (double)colsum_a[32];
            double Md    = (double)Mrows;
            mean_s = (float)((Md * q2sum + 64.0 * sumsq - 2.0 * (double)dq) / (64.0 * Md));
        }
    }
    __syncthreads();

    float lst[10];
    #pragma unroll
    for (int i = 0; i < 10; ++i) lst[i] = -FLT_MAX;
    const float* pt = part_top + (size_t)b * nb * 10;
    for (int i = tid; i < nb; i += 256) {
        const float* pp = pt + (size_t)i * 10;
        #pragma unroll
        for (int r = 0; r < 10; ++r) top10_insert(lst, pp[r]);
    }
    #pragma unroll
    for (int r = 0; r < 10; ++r) smem[tid * 10 + r] = lst[r];
    __syncthreads();

    if (tid < 32) {
        float m[10];
        #pragma unroll
        for (int i = 0; i < 10; ++i) m[i] = -FLT_MAX;
        for (int j2 = 0; j2 < 8; ++j2) {
            #pragma unroll
            for (int r = 0; r < 10; ++r) top10_insert(m, smem[(tid * 8 + j2) * 10 + r]);
        }
        #pragma unroll
        for (int r = 0; r < 10; ++r) smem[2560 + tid * 10 + r] = m[r];
    }
    __syncthreads();

    if (tid == 0) {
        float m[10];
        #pragma unroll
        for (int i = 0; i < 10; ++i) m[i] = -FLT_MAX;
        for (int j2 = 0; j2 < 32; ++j2) {
            #pragma unroll
            for (int r = 0; r < 10; ++r) top10_insert(m, smem[2560 + j2 * 10 + r]);
        }
        const float mean = mean_s;
        const float q2b  = q2_s;
        float sum = 0.f;
        #pragma unroll
        for (int r = 0; r < 10; ++r) {
            float sq = m[r] + q2b;
            sq = fmaxf(sq, 0.f);
            sum += KEPS / (sq / mean + KEPS);
        }
        out[b] = 1.0f / sqrtf(sum + DENOMC);
    }
}

// ---------------------------------------------------------------------------
extern "C" void kernel_launch(void* const* d_in, const int* in_sizes, int n_in,
                              void* d_out, int out_size, void* d_ws, size_t ws_size,
                              hipStream_t stream)
{
    const float* q   = (const float*)d_in[0];
    const float* mem = (const float*)d_in[1];
    float* out = (float*)d_out;

    const int Mrows  = in_sizes[1] / 32;   // 2,000,000
    const int ntiles = Mrows / 64;         // 31,250

    int nb = 1280;                         // 256 CUs x 5 resident blocks
    while (nb > 64 && ((size_t)nb * 673 + 64) * sizeof(float) > ws_size) nb >>= 1;
    if (nb > ntiles) nb = ntiles;

    float* part_top  = (float*)d_ws;                         // [64][nb][10]
    float* part_sums = part_top + (size_t)64 * nb * 10;      // [33][nb]

    ep_main<<<dim3(nb), dim3(256), 0, stream>>>(q, mem, part_top, part_sums, nb, ntiles);
    ep_tail<<<dim3(64), dim3(256), 0, stream>>>(q, part_top, part_sums, out, nb, Mrows);
}